// Round 15
// baseline (90.534 us; speedup 1.0000x reference)
//
#include <hip/hip_runtime.h>

// TopKRouter: N=32768 tokens, D=2048, E=64, K=2.
// R15 = R14's counted-vmcnt pipeline with 8-wave blocks (512 thr):
//  - wave = 16 tokens x 32 experts (2 etiles, acc[2]); 4 waves/SIMD at
//    2 blocks/CU doubles latency overlap vs R14.
//  - per-thread staging: 1 x cp16 + 1 w cp16 per stage; steady vmcnt(4)
//    keeps 2 stages (32 KB) in flight. Tail 2 -> 0.
//  - 4-deep 16KB LDS ring, XOR-swizzled x, fragment-ordered w,
//    fp16x2-split MFMA (hh,hl,lh,ll; K ascending) == R12/R14 bit-identical.

#define NTOK 32768
#define DDIM 2048
#define NEXP 64
#define NKS 64              // K steps of 32
#define LG_STRIDE 68        // 64 + 4 pad

#define OFF_IDX 0
#define OFF_W 65536
#define OFF_CNT 131072
#define OFF_OVF 131136
#define OFF_ZL 131137
#define OFF_ENT 131138
#define OFF_VAR 131139
#define OFF_CONF 131140

#define WS_PLANES_OFF 1024
#define WS_NEEDED (WS_PLANES_OFF + NKS * 8192)  // 1 KB + 512 KB

struct RouterWS {
  unsigned int counts[NEXP];
  double z_sum;
  double ent_sum;
};

typedef _Float16 half8 __attribute__((ext_vector_type(8)));
typedef float floatx4 __attribute__((ext_vector_type(4)));

typedef __attribute__((address_space(1))) void v1_t;
typedef __attribute__((address_space(3))) void v3_t;
__device__ __forceinline__ void cp16(const void* g, void* l) {
  __builtin_amdgcn_global_load_lds((v1_t*)g, (v3_t*)l, 16, 0, 0);
}

// ---- prologue: split w*256 into 2 fp16 planes, fragment-ordered ----
// plane layout (halves): [s][p][t][l][8] ; lane l of etile t covers
// w[e=16t+(l&15)][k=32s+(l>>4)*8 .. +7].
__global__ void convert_w(const float* __restrict__ w, _Float16* __restrict__ wp) {
  int tid = blockIdx.x * 256 + threadIdx.x;  // 0..16383
  int l = tid & 63;
  int t = (tid >> 6) & 3;
  int s = tid >> 8;
  int e = 16 * t + (l & 15);
  int k0 = 32 * s + (l >> 4) * 8;
  const float* src = w + (size_t)e * DDIM + k0;
  half8 h, lo;
#pragma unroll
  for (int i = 0; i < 8; ++i) {
    float v = src[i] * 256.0f;
    _Float16 hh = (_Float16)v;
    h[i] = hh;
    lo[i] = (_Float16)(v - (float)hh);
  }
  size_t base = (size_t)s * 4096 + ((size_t)t * 64 + l) * 8;
  *(half8*)(wp + base) = h;
  *(half8*)(wp + base + 2048) = lo;  // plane 1
}

// ---- main MFMA kernel ----
__global__ __launch_bounds__(512, 4) void router_mfma(
    const float* __restrict__ x, const _Float16* __restrict__ wp,
    float* __restrict__ out, RouterWS* __restrict__ ws) {
  // 4 ring buffers x 16KB: [0,8K) x-tile (swizzled), [8K,16K) w hi|lo.
  // After the K loop, lg[64][68] (17.4KB) aliases the front.
  __shared__ __align__(16) char smem[65536];
  __shared__ unsigned int hist[NEXP];

  const int tid = threadIdx.x;                              // 0..511
  const int l = tid & 63;
  const int wv = __builtin_amdgcn_readfirstlane(tid >> 6);  // wave 0..7
  const int m = wv & 3;                                     // m-tile (16 tokens)
  const int eg = wv >> 2;                                   // etile pair 0..1
  const int r = l & 15;                                     // token row / expert col
  const int g = l >> 4;                                     // k-group

  const int tokb = blockIdx.x * 64;
  const float* xg = x + (size_t)tokb * DDIM;

  // x staging: thread stages slot tid (512 slots = 8 KB); slot i holds
  // x[row=i>>3][col4 = (i&7)^(row&7)] — pre-swizzled source, linear dest.
  const int srow = tid >> 3;
  const int sj = tid & 7;
  const size_t gx = (size_t)srow * DDIM + 4 * (sj ^ (srow & 7));

  // read constants: lane (r,g) of m-tile m reads row=m*16+r, cols 2g,2g+1
  const int row = m * 16 + r;
  const int rs = row & 7;
  const int so0 = 16 * (row * 8 + ((2 * g) ^ rs));
  const int so1 = 16 * (row * 8 + ((2 * g + 1) ^ rs));
  const int wlo = 16 * l;

  floatx4 acc[2];
#pragma unroll
  for (int t = 0; t < 2; ++t) {
    floatx4 z = {0.f, 0.f, 0.f, 0.f};
    acc[t] = z;
  }

#define STAGE(S, BUF)                                                          \
  {                                                                            \
    char* bb_ = smem + (BUF) * 16384;                                          \
    cp16(xg + (size_t)(S) * 32 + gx, bb_ + tid * 16);                          \
    cp16((const char*)wp + (size_t)(S) * 8192 + tid * 16,                      \
         bb_ + 8192 + tid * 16);                                               \
  }

#define WAITBAR(NW)                                                            \
  asm volatile("s_waitcnt vmcnt(" #NW ")\n\ts_barrier" ::: "memory");          \
  __builtin_amdgcn_sched_barrier(0);

#define CVT8(X0, X1, XH, XL)                                                   \
  {                                                                            \
    float vv[8] = {X0.x, X0.y, X0.z, X0.w, X1.x, X1.y, X1.z, X1.w};            \
    _Pragma("unroll") for (int i = 0; i < 8; ++i) {                            \
      _Float16 hh = (_Float16)vv[i];                                           \
      XH[i] = hh;                                                              \
      XL[i] = (_Float16)(vv[i] - (float)hh);                                   \
    }                                                                          \
  }

#define COMPUTE(BUF)                                                           \
  const char* bb = smem + (BUF) * 16384;                                       \
  float4 xq0 = *(const float4*)(bb + so0);                                     \
  float4 xq1 = *(const float4*)(bb + so1);                                     \
  half8 xh, xl;                                                                \
  CVT8(xq0, xq1, xh, xl);                                                      \
  _Pragma("unroll") for (int t = 0; t < 2; ++t) { /* etile = 2*eg + t */       \
    const char* wb_ = bb + 8192 + 1024 * (2 * eg + t);                         \
    half8 wh = *(const half8*)(wb_ + wlo);                                     \
    half8 wl = *(const half8*)(wb_ + 4096 + wlo);                              \
    acc[t] = __builtin_amdgcn_mfma_f32_16x16x32_f16(xh, wh, acc[t], 0, 0, 0);  \
    acc[t] = __builtin_amdgcn_mfma_f32_16x16x32_f16(xh, wl, acc[t], 0, 0, 0);  \
    acc[t] = __builtin_amdgcn_mfma_f32_16x16x32_f16(xl, wh, acc[t], 0, 0, 0);  \
    acc[t] = __builtin_amdgcn_mfma_f32_16x16x32_f16(xl, wl, acc[t], 0, 0, 0);  \
  }

#define STEP(S, BUF, NW)                                                       \
  {                                                                            \
    STAGE((S) + 3, (((S) + 3) & 3));                                           \
    COMPUTE(BUF)                                                               \
    WAITBAR(NW)                                                                \
  }
#define STEPN(S, BUF, NW)  /* tail: no stage */                                \
  {                                                                            \
    COMPUTE(BUF)                                                               \
    WAITBAR(NW)                                                                \
  }

  // prologue: stages 0,1,2 in flight (6 loads/thread); wait stage 0 (4 left).
  STAGE(0, 0)
  STAGE(1, 1)
  STAGE(2, 2)
  if (tid < NEXP) hist[tid] = 0;
  WAITBAR(4)

  for (int ss = 0; ss < 60; ss += 4) {  // steps 0..59, stage s+3 each
    STEP(ss, 0, 4)
    STEP(ss + 1, 1, 4)
    STEP(ss + 2, 2, 4)
    STEP(ss + 3, 3, 4)
  }
  STEP(60, 0, 4)    // stages 63; 62,63 in flight after wait
  STEPN(61, 1, 2)   // wait stage 62
  STEPN(62, 2, 0)   // wait stage 63
  {                 // step 63: nothing outstanding
    COMPUTE(3)
  }
  __syncthreads();

#undef STEP
#undef STEPN
#undef COMPUTE
#undef CVT8
#undef WAITBAR
#undef STAGE

  // C layout (HW-verified): col = lane&15, row = (lane>>4)*4 + j.
  // lg[token][expert]: token = m*16 + g*4 + j, expert = 16*(2eg+t) + r. /256.
  float* lg = (float*)smem;
#pragma unroll
  for (int t = 0; t < 2; ++t)
#pragma unroll
    for (int j = 0; j < 4; ++j)
      lg[(m * 16 + g * 4 + j) * LG_STRIDE + 16 * (2 * eg + t) + r] =
          acc[t][j] * 0.00390625f;
  __syncthreads();

  if (tid < 64) {  // wave 0: one token per lane, serial over 64 experts
    const int t = tid;
    const float* Lg = &lg[t * LG_STRIDE];

    float m1 = Lg[0];
    int i1 = 0;
    for (int e = 1; e < NEXP; ++e) {
      float v = Lg[e];
      if (v > m1) { m1 = v; i1 = e; }  // strict > keeps lowest index on ties
    }
    float m2 = -3.4e38f;
    int i2 = 0;
    for (int e = 0; e < NEXP; ++e) {
      if (e == i1) continue;
      float v = Lg[e];
      if (v > m2) { m2 = v; i2 = e; }
    }

    float s = 0.f;
    for (int e = 0; e < NEXP; ++e) s += expf(Lg[e] - m1);
    float p1 = expf(Lg[i1] - m1) / s;
    float p2 = expf(Lg[i2] - m1) / s;
    float wsum = p1 + p2 + 1e-8f;
    float w1 = p1 / wsum;
    float w2 = p2 / wsum;

    float ent = 0.f;
    for (int e = 0; e < NEXP; ++e) {
      float p = expf(Lg[e] - m1) / s;
      ent -= p * logf(p + 1e-10f);
    }
    float lse = m1 + logf(s);

    size_t gt = (size_t)blockIdx.x * 64 + t;
    out[OFF_IDX + gt * 2 + 0] = (float)i1;
    out[OFF_IDX + gt * 2 + 1] = (float)i2;
    out[OFF_W + gt * 2 + 0] = w1;
    out[OFF_W + gt * 2 + 1] = w2;
    out[OFF_CONF + gt] = fmaxf(w1, w2);

    atomicAdd(&hist[i1], 1u);
    atomicAdd(&hist[i2], 1u);

    float zv = lse, ev = ent;
#pragma unroll
    for (int o = 32; o > 0; o >>= 1) {
      zv += __shfl_down(zv, o);
      ev += __shfl_down(ev, o);
    }
    if (t == 0) {
      atomicAdd(&ws->z_sum, (double)zv);
      atomicAdd(&ws->ent_sum, (double)ev);
    }
  }
  __syncthreads();
  if (tid < NEXP) atomicAdd(&ws->counts[tid], hist[tid]);
}

// ---- fp32 fallback (R10) if ws too small for planes ----
#define TTILE 128
#define KB 32
#define NCH (DDIM / KB)
#define XSTR 36
#define XBUF (TTILE * XSTR)
#define WBUF (NEXP * XSTR)
#define WOFF (2 * XBUF)

__global__ __launch_bounds__(512, 4) void router_fp32(
    const float* __restrict__ x, const float* __restrict__ w,
    float* __restrict__ out, RouterWS* __restrict__ ws) {
  __shared__ float smem[2 * XBUF + 2 * WBUF];
  __shared__ unsigned int hist[NEXP];

  const int tid = threadIdx.x;
  const int L = tid & 63;
  const int wv = __builtin_amdgcn_readfirstlane(tid >> 6);
  const float* xg = x + (size_t)blockIdx.x * TTILE * DDIM;
  const int sr = tid >> 3;
  const int sc = (tid & 7) * 4;

  float4 rx0 = *(const float4*)(xg + (size_t)sr * DDIM + sc);
  float4 rx1 = *(const float4*)(xg + (size_t)(sr + 64) * DDIM + sc);
  float4 rw = *(const float4*)(w + (size_t)sr * DDIM + sc);
  *(float4*)&smem[sr * XSTR + sc] = rx0;
  *(float4*)&smem[(sr + 64) * XSTR + sc] = rx1;
  *(float4*)&smem[WOFF + sr * XSTR + sc] = rw;

  float acc0[8], acc1[8];
#pragma unroll
  for (int e = 0; e < 8; ++e) { acc0[e] = 0.f; acc1[e] = 0.f; }
  __syncthreads();

  for (int c = 0; c < NCH; ++c) {
    const int cxb = (c & 1) * XBUF;
    const int cwb = WOFF + (c & 1) * WBUF;
    if (c + 1 < NCH) {
      int k0 = (c + 1) * KB;
      rx0 = *(const float4*)(xg + (size_t)sr * DDIM + k0 + sc);
      rx1 = *(const float4*)(xg + (size_t)(sr + 64) * DDIM + k0 + sc);
      rw = *(const float4*)(w + (size_t)sr * DDIM + k0 + sc);
    }
    float4 xr0[8], xr1[8];
#pragma unroll
    for (int m = 0; m < 8; ++m) {
      xr0[m] = *(const float4*)&smem[cxb + L * XSTR + 4 * m];
      xr1[m] = *(const float4*)&smem[cxb + (L + 64) * XSTR + 4 * m];
    }
#pragma unroll
    for (int e = 0; e < 8; ++e) {
      const float* wrow = &smem[cwb + (8 * wv + e) * XSTR];
      float a0 = acc0[e], a1 = acc1[e];
#pragma unroll
      for (int m = 0; m < 8; ++m) {
        float4 wq = *(const float4*)&wrow[4 * m];
        a0 = fmaf(xr0[m].x, wq.x, a0);
        a0 = fmaf(xr0[m].y, wq.y, a0);
        a0 = fmaf(xr0[m].z, wq.z, a0);
        a0 = fmaf(xr0[m].w, wq.w, a0);
        a1 = fmaf(xr1[m].x, wq.x, a1);
        a1 = fmaf(xr1[m].y, wq.y, a1);
        a1 = fmaf(xr1[m].z, wq.z, a1);
        a1 = fmaf(xr1[m].w, wq.w, a1);
      }
      acc0[e] = a0;
      acc1[e] = a1;
    }
    if (c + 1 < NCH) {
      const int nxb = ((c + 1) & 1) * XBUF;
      const int nwb = WOFF + ((c + 1) & 1) * WBUF;
      *(float4*)&smem[nxb + sr * XSTR + sc] = rx0;
      *(float4*)&smem[nxb + (sr + 64) * XSTR + sc] = rx1;
      *(float4*)&smem[nwb + sr * XSTR + sc] = rw;
    }
    __syncthreads();
  }

#pragma unroll
  for (int e = 0; e < 8; ++e) {
    smem[L * LG_STRIDE + wv * 8 + e] = acc0[e];
    smem[(L + 64) * LG_STRIDE + wv * 8 + e] = acc1[e];
  }
  if (tid < NEXP) hist[tid] = 0;
  __syncthreads();

  if (tid < TTILE) {
    const int t = tid;
    const float* Lg = &smem[t * LG_STRIDE];
    float m1 = Lg[0];
    int i1 = 0;
    for (int e = 1; e < NEXP; ++e) {
      float v = Lg[e];
      if (v > m1) { m1 = v; i1 = e; }
    }
    float m2 = -3.4e38f;
    int i2 = 0;
    for (int e = 0; e < NEXP; ++e) {
      if (e == i1) continue;
      float v = Lg[e];
      if (v > m2) { m2 = v; i2 = e; }
    }
    float s = 0.f;
    for (int e = 0; e < NEXP; ++e) s += expf(Lg[e] - m1);
    float p1 = expf(Lg[i1] - m1) / s;
    float p2 = expf(Lg[i2] - m1) / s;
    float wsum = p1 + p2 + 1e-8f;
    float w1 = p1 / wsum;
    float w2 = p2 / wsum;
    float ent = 0.f;
    for (int e = 0; e < NEXP; ++e) {
      float p = expf(Lg[e] - m1) / s;
      ent -= p * logf(p + 1e-10f);
    }
    float lse = m1 + logf(s);
    size_t gt = (size_t)blockIdx.x * TTILE + t;
    out[OFF_IDX + gt * 2 + 0] = (float)i1;
    out[OFF_IDX + gt * 2 + 1] = (float)i2;
    out[OFF_W + gt * 2 + 0] = w1;
    out[OFF_W + gt * 2 + 1] = w2;
    out[OFF_CONF + gt] = fmaxf(w1, w2);
    atomicAdd(&hist[i1], 1u);
    atomicAdd(&hist[i2], 1u);
    float zv = lse, ev = ent;
#pragma unroll
    for (int o = 32; o > 0; o >>= 1) {
      zv += __shfl_down(zv, o);
      ev += __shfl_down(ev, o);
    }
    if ((tid & 63) == 0) {
      atomicAdd(&ws->z_sum, (double)zv);
      atomicAdd(&ws->ent_sum, (double)ev);
    }
  }
  __syncthreads();
  if (tid < NEXP) atomicAdd(&ws->counts[tid], hist[tid]);
}

__global__ void router_final(float* __restrict__ out, RouterWS* __restrict__ ws) {
  int e = threadIdx.x;  // 64 threads
  float c = (float)ws->counts[e];
  out[OFF_CNT + e] = c;
  float over = fmaxf(c - 1280.f, 0.f);   // capacity = int(1.25*32768/64*2)
  float ld = c / 65536.f - (1.f / 64.f);
  float so = over, sv = ld * ld;
#pragma unroll
  for (int o = 32; o > 0; o >>= 1) {
    so += __shfl_down(so, o);
    sv += __shfl_down(sv, o);
  }
  if (e == 0) {
    out[OFF_OVF] = so / 32768.f * 100.f;
    out[OFF_VAR] = sv / 64.f;
    out[OFF_ZL] = (float)(ws->z_sum / 32768.0 * 0.01);
    out[OFF_ENT] = (float)(ws->ent_sum / 32768.0);
  }
}

extern "C" void kernel_launch(void* const* d_in, const int* in_sizes, int n_in,
                              void* d_out, int out_size, void* d_ws, size_t ws_size,
                              hipStream_t stream) {
  const float* x = (const float*)d_in[0];   // hidden_states [4,8192,2048] f32
  const float* w = (const float*)d_in[1];   // gate_weight [64,2048] f32
  float* out = (float*)d_out;
  RouterWS* ws = (RouterWS*)d_ws;

  (void)hipMemsetAsync(d_ws, 0, sizeof(RouterWS), stream);
  if (ws_size >= (size_t)WS_NEEDED) {
    _Float16* wp = (_Float16*)((char*)d_ws + WS_PLANES_OFF);
    hipLaunchKernelGGL(convert_w, dim3(64), dim3(256), 0, stream, w, wp);
    hipLaunchKernelGGL(router_mfma, dim3(NTOK / 64), dim3(512), 0, stream,
                       x, wp, out, ws);
  } else {
    hipLaunchKernelGGL(router_fp32, dim3(NTOK / TTILE), dim3(512), 0, stream,
                       x, w, out, ws);
  }
  hipLaunchKernelGGL(router_final, dim3(1), dim3(64), 0, stream, out, ws);
}

// Round 16
// 90.450 us; speedup vs baseline: 1.0009x; 1.0009x over previous
//
#include <hip/hip_runtime.h>

// TopKRouter: N=32768 tokens, D=2048, E=64, K=2.
// R16 = R14's counted-vmcnt MFMA pipeline with:
//  - KB=64 (32 steps, 32 barriers; 32 MFMA/wave/step)
//  - x: 3-deep 16KB LDS ring via global_load_lds (stage s+2 at step s,
//    end-wait vmcnt(4) keeps 1 stage in flight)
//  - w: converted fp32->fp16 hi/lo planes IN-KERNEL per step (coalesced
//    L2 reads, reg cvt, ds_write to 2x16KB w-LDS) — no prologue kernel.
//  - fp16x2-split MFMA (hh,hl,lh,ll; k-chunks ascending) == R12/R14
//    bit-identical logits.

#define NTOK 32768
#define DDIM 2048
#define NEXP 64
#define NST 32              // K steps of 64
#define LG_STRIDE 68        // 64 + 4 pad

#define OFF_IDX 0
#define OFF_W 65536
#define OFF_CNT 131072
#define OFF_OVF 131136
#define OFF_ZL 131137
#define OFF_ENT 131138
#define OFF_VAR 131139
#define OFF_CONF 131140

#define XRING 49152         // 3 x 16384
#define WBOFF XRING         // w buffers start

struct RouterWS {
  unsigned int counts[NEXP];
  double z_sum;
  double ent_sum;
};

typedef _Float16 half8 __attribute__((ext_vector_type(8)));
typedef float floatx4 __attribute__((ext_vector_type(4)));

typedef __attribute__((address_space(1))) void v1_t;
typedef __attribute__((address_space(3))) void v3_t;
__device__ __forceinline__ void cp16(const void* g, void* l) {
  __builtin_amdgcn_global_load_lds((v1_t*)g, (v3_t*)l, 16, 0, 0);
}

__global__ __launch_bounds__(256, 2) void router_mfma(
    const float* __restrict__ x, const float* __restrict__ w,
    float* __restrict__ out, RouterWS* __restrict__ ws) {
  // [0,49152): x ring 3x16KB (each: half0 8KB | half1 8KB, XOR-swizzled)
  // [49152,81920): w bufs 2x16KB ([h][p][t][lane][8] halves)
  // After K-loop: lg[64][68] aliases x-ring; hist aliases w region.
  __shared__ __align__(16) char smem[81920];

  const int tid = threadIdx.x;                              // 0..255
  const int l = tid & 63;
  const int wv = __builtin_amdgcn_readfirstlane(tid >> 6);  // m-tile 0..3
  const int r = l & 15;                                     // token row / expert col
  const int g = l >> 4;                                     // k-group

  const float* xg = x + (size_t)blockIdx.x * 64 * DDIM;

  // ---- x staging map (per R14, proven): thread stages slots tid, tid+256
  // in each 8KB half; slot i = row*8 + (j ^ (row&7)) float4s, linear dest.
  const int srow0 = tid >> 3;               // 0..31
  const int srow1 = srow0 + 32;             // 32..63 ((row&7) unchanged)
  const int sj = tid & 7;
  const size_t gx0 = (size_t)srow0 * DDIM + 4 * (sj ^ (srow0 & 7));
  const size_t gx1 = (size_t)srow1 * DDIM + 4 * (sj ^ (srow1 & 7));

  // ---- x read offsets: lane (r,g) of wave wv reads row, float4 cols 2g,2g+1
  const int row = wv * 16 + r;
  const int rs = row & 7;
  const int so0 = 16 * (row * 8 + ((2 * g) ^ rs));
  const int so1 = 16 * (row * 8 + ((2 * g + 1) ^ rs));
  const int wlo = 16 * l;

  // ---- w conversion map: thread tid converts w[e=tid>>2][16c..16c+15]
  // (c=tid&3) of each step -> 2 hi + 2 lo fragments.
  const int we = tid >> 2;
  const int wc = tid & 3;
  const float* wsrc = w + (size_t)we * DDIM + 16 * wc;
  const int cwh = wc >> 1;                   // half
  const int cwt = we >> 4;                   // etile
  const int cl0 = ((2 * (wc & 1)) << 4) | (we & 15);
  const int cl1 = ((2 * (wc & 1) + 1) << 4) | (we & 15);
  const int wd0 = cwh * 8192 + cwt * 1024 + cl0 * 16;  // hi octet0 (lo:+4096)
  const int wd1 = cwh * 8192 + cwt * 1024 + cl1 * 16;

  floatx4 acc[4];
#pragma unroll
  for (int t = 0; t < 4; ++t) {
    floatx4 z = {0.f, 0.f, 0.f, 0.f};
    acc[t] = z;
  }

  float4 wf0, wf1, wf2, wf3;  // w fp32 in flight (for step s+1)

#define WLOAD(S)                                                               \
  {                                                                            \
    const float* p_ = wsrc + (size_t)(S) * 64;                                 \
    wf0 = *(const float4*)(p_ + 0);                                            \
    wf1 = *(const float4*)(p_ + 4);                                            \
    wf2 = *(const float4*)(p_ + 8);                                            \
    wf3 = *(const float4*)(p_ + 12);                                           \
  }

#define STAGE_X(S, XB)                                                         \
  {                                                                            \
    char* bb_ = smem + (XB) * 16384;                                           \
    const float* xs_ = xg + (size_t)(S) * 64;                                  \
    cp16(xs_ + gx0, bb_ + tid * 16);                                           \
    cp16(xs_ + gx1, bb_ + (tid + 256) * 16);                                   \
    cp16(xs_ + gx0 + 32, bb_ + 8192 + tid * 16);                               \
    cp16(xs_ + gx1 + 32, bb_ + 8192 + (tid + 256) * 16);                       \
  }

#define WCVT(WB)                                                               \
  {                                                                            \
    float vv_[16] = {wf0.x, wf0.y, wf0.z, wf0.w, wf1.x, wf1.y, wf1.z, wf1.w,   \
                     wf2.x, wf2.y, wf2.z, wf2.w, wf3.x, wf3.y, wf3.z, wf3.w};  \
    half8 h0_, h1_, lo0_, lo1_;                                                \
    _Pragma("unroll") for (int i = 0; i < 8; ++i) {                            \
      float v_ = vv_[i] * 256.0f;                                              \
      _Float16 hh_ = (_Float16)v_;                                             \
      h0_[i] = hh_;                                                            \
      lo0_[i] = (_Float16)(v_ - (float)hh_);                                   \
      float u_ = vv_[8 + i] * 256.0f;                                          \
      _Float16 uh_ = (_Float16)u_;                                             \
      h1_[i] = uh_;                                                            \
      lo1_[i] = (_Float16)(u_ - (float)uh_);                                   \
    }                                                                          \
    char* wbb_ = smem + WBOFF + (WB) * 16384;                                  \
    *(half8*)(wbb_ + wd0) = h0_;                                               \
    *(half8*)(wbb_ + wd0 + 4096) = lo0_;                                       \
    *(half8*)(wbb_ + wd1) = h1_;                                               \
    *(half8*)(wbb_ + wd1 + 4096) = lo1_;                                       \
  }

#define WAITBAR(NW)                                                            \
  asm volatile("s_waitcnt vmcnt(" #NW ") lgkmcnt(0)\n\ts_barrier" :::          \
               "memory");                                                      \
  __builtin_amdgcn_sched_barrier(0);

#define CVT8(X0, X1, XH, XL)                                                   \
  {                                                                            \
    float vv[8] = {X0.x, X0.y, X0.z, X0.w, X1.x, X1.y, X1.z, X1.w};            \
    _Pragma("unroll") for (int i = 0; i < 8; ++i) {                            \
      _Float16 hh = (_Float16)vv[i];                                           \
      XH[i] = hh;                                                              \
      XL[i] = (_Float16)(vv[i] - (float)hh);                                   \
    }                                                                          \
  }

#define COMPUTE(XB, WB)                                                        \
  {                                                                            \
    const char* xb_ = smem + (XB) * 16384;                                     \
    const char* wb_ = smem + WBOFF + (WB) * 16384;                             \
    _Pragma("unroll") for (int h = 0; h < 2; ++h) {                            \
      float4 xq0 = *(const float4*)(xb_ + h * 8192 + so0);                     \
      float4 xq1 = *(const float4*)(xb_ + h * 8192 + so1);                     \
      half8 xh, xl;                                                            \
      CVT8(xq0, xq1, xh, xl);                                                  \
      _Pragma("unroll") for (int t = 0; t < 4; ++t) {                          \
        half8 wh8 = *(const half8*)(wb_ + h * 8192 + t * 1024 + wlo);          \
        half8 wl8 = *(const half8*)(wb_ + h * 8192 + 4096 + t * 1024 + wlo);   \
        acc[t] =                                                               \
            __builtin_amdgcn_mfma_f32_16x16x32_f16(xh, wh8, acc[t], 0, 0, 0);  \
        acc[t] =                                                               \
            __builtin_amdgcn_mfma_f32_16x16x32_f16(xh, wl8, acc[t], 0, 0, 0);  \
        acc[t] =                                                               \
            __builtin_amdgcn_mfma_f32_16x16x32_f16(xl, wh8, acc[t], 0, 0, 0);  \
        acc[t] =                                                               \
            __builtin_amdgcn_mfma_f32_16x16x32_f16(xl, wl8, acc[t], 0, 0, 0);  \
      }                                                                        \
    }                                                                          \
  }

  // STEPF: compute step S from (XI, WI); stage x S+2 into XN; load+cvt w S+1
  // into WI^1. End-wait vmcnt(4): x stage S+1 landed (S+2's 4 loads remain).
#define STEPF(S, XI, WI, XN)                                                   \
  {                                                                            \
    WLOAD((S) + 1)                                                             \
    STAGE_X((S) + 2, XN)                                                       \
    COMPUTE(XI, WI)                                                            \
    WCVT((WI) ^ 1)                                                             \
    WAITBAR(4)                                                                 \
  }

  // ---- prologue: w step 0 + x stages 0,1; cvt waits vmcnt(8) (x flies) ----
  WLOAD(0)
  STAGE_X(0, 0)
  STAGE_X(1, 1)
  WCVT(0)
  WAITBAR(4)

  for (int b = 0; b < 30; b += 6) {  // steps b..b+5; ring/buf indices static
    STEPF(b + 0, 0, 0, 2)
    STEPF(b + 1, 1, 1, 0)
    STEPF(b + 2, 2, 0, 1)
    STEPF(b + 3, 0, 1, 2)
    STEPF(b + 4, 1, 0, 0)
    STEPF(b + 5, 2, 1, 1)
  }
  {  // step 30: no x stage; w 31; cvt drains x31 too (needed anyway)
    WLOAD(31)
    COMPUTE(0, 0)
    WCVT(1)
    WAITBAR(0)
  }
  COMPUTE(1, 1)  // step 31: everything resident
  __syncthreads();

#undef STEPF
#undef COMPUTE
#undef CVT8
#undef WAITBAR
#undef WCVT
#undef STAGE_X
#undef WLOAD

  // C layout (HW-verified): col = lane&15, row = (lane>>4)*4 + j.
  // lg[token][expert]: token = wv*16 + g*4 + j, expert = 16t + r. Scale 1/256.
  float* lg = (float*)smem;
  unsigned int* hist = (unsigned int*)(smem + WBOFF);  // w region dead now
#pragma unroll
  for (int t = 0; t < 4; ++t)
#pragma unroll
    for (int j = 0; j < 4; ++j)
      lg[(wv * 16 + g * 4 + j) * LG_STRIDE + 16 * t + r] = acc[t][j] * 0.00390625f;
  if (tid < NEXP) hist[tid] = 0;
  __syncthreads();

  if (tid < 64) {  // wave 0: one token per lane, serial over 64 experts
    const int t = tid;
    const float* Lg = &lg[t * LG_STRIDE];

    float m1 = Lg[0];
    int i1 = 0;
    for (int e = 1; e < NEXP; ++e) {
      float v = Lg[e];
      if (v > m1) { m1 = v; i1 = e; }  // strict > keeps lowest index on ties
    }
    float m2 = -3.4e38f;
    int i2 = 0;
    for (int e = 0; e < NEXP; ++e) {
      if (e == i1) continue;
      float v = Lg[e];
      if (v > m2) { m2 = v; i2 = e; }
    }

    float s = 0.f;
    for (int e = 0; e < NEXP; ++e) s += expf(Lg[e] - m1);
    float p1 = expf(Lg[i1] - m1) / s;
    float p2 = expf(Lg[i2] - m1) / s;
    float wsum = p1 + p2 + 1e-8f;
    float w1 = p1 / wsum;
    float w2 = p2 / wsum;

    float ent = 0.f;
    for (int e = 0; e < NEXP; ++e) {
      float p = expf(Lg[e] - m1) / s;
      ent -= p * logf(p + 1e-10f);
    }
    float lse = m1 + logf(s);

    size_t gt = (size_t)blockIdx.x * 64 + t;
    out[OFF_IDX + gt * 2 + 0] = (float)i1;
    out[OFF_IDX + gt * 2 + 1] = (float)i2;
    out[OFF_W + gt * 2 + 0] = w1;
    out[OFF_W + gt * 2 + 1] = w2;
    out[OFF_CONF + gt] = fmaxf(w1, w2);

    atomicAdd(&hist[i1], 1u);
    atomicAdd(&hist[i2], 1u);

    float zv = lse, ev = ent;
#pragma unroll
    for (int o = 32; o > 0; o >>= 1) {
      zv += __shfl_down(zv, o);
      ev += __shfl_down(ev, o);
    }
    if (t == 0) {
      atomicAdd(&ws->z_sum, (double)zv);
      atomicAdd(&ws->ent_sum, (double)ev);
    }
  }
  __syncthreads();
  if (tid < NEXP) atomicAdd(&ws->counts[tid], hist[tid]);
}

__global__ void router_final(float* __restrict__ out, RouterWS* __restrict__ ws) {
  int e = threadIdx.x;  // 64 threads
  float c = (float)ws->counts[e];
  out[OFF_CNT + e] = c;
  float over = fmaxf(c - 1280.f, 0.f);   // capacity = int(1.25*32768/64*2)
  float ld = c / 65536.f - (1.f / 64.f);
  float so = over, sv = ld * ld;
#pragma unroll
  for (int o = 32; o > 0; o >>= 1) {
    so += __shfl_down(so, o);
    sv += __shfl_down(sv, o);
  }
  if (e == 0) {
    out[OFF_OVF] = so / 32768.f * 100.f;
    out[OFF_VAR] = sv / 64.f;
    out[OFF_ZL] = (float)(ws->z_sum / 32768.0 * 0.01);
    out[OFF_ENT] = (float)(ws->ent_sum / 32768.0);
  }
}

extern "C" void kernel_launch(void* const* d_in, const int* in_sizes, int n_in,
                              void* d_out, int out_size, void* d_ws, size_t ws_size,
                              hipStream_t stream) {
  const float* x = (const float*)d_in[0];   // hidden_states [4,8192,2048] f32
  const float* w = (const float*)d_in[1];   // gate_weight [64,2048] f32
  float* out = (float*)d_out;
  RouterWS* ws = (RouterWS*)d_ws;

  (void)hipMemsetAsync(d_ws, 0, sizeof(RouterWS), stream);
  hipLaunchKernelGGL(router_mfma, dim3(NTOK / 64), dim3(256), 0, stream,
                     x, w, out, ws);
  hipLaunchKernelGGL(router_final, dim3(1), dim3(64), 0, stream, out, ws);
}

// Round 17
// 82.288 us; speedup vs baseline: 1.1002x; 1.0992x over previous
//
#include <hip/hip_runtime.h>

// TopKRouter: N=32768 tokens, D=2048, E=64, K=2.
// R17 = R14 champion with x taken OUT of LDS:
//  - x: wave-private fragments loaded straight to registers (2 b128/step,
//    depth-2 ping-pong, 16-row x 128B coalesced) — no cp16, no ds_read, no
//    swizzle for x.
//  - w: unchanged R14 path — convert_w prologue (fp16 hi/lo planes, fragment
//    ordered), 4-deep 8KB LDS ring via global_load_lds, broadcast ds_reads.
//  - counted-vmcnt schedule for 4 vmem instrs/wave/step: prologue 4; step0 6;
//    steps 1..60 -> 8; tail 6,2,0. sched_barrier(0) pins step boundaries.
//  - fp16x2-split MFMA (hh,hl,lh,ll; K ascending): bit-identical to R12/R14.

#define NTOK 32768
#define DDIM 2048
#define NEXP 64
#define NKS 64              // K steps of 32
#define LG_STRIDE 68        // 64 + 4 pad

#define OFF_IDX 0
#define OFF_W 65536
#define OFF_CNT 131072
#define OFF_OVF 131136
#define OFF_ZL 131137
#define OFF_ENT 131138
#define OFF_VAR 131139
#define OFF_CONF 131140

#define WS_PLANES_OFF 1024
#define WS_NEEDED (WS_PLANES_OFF + NKS * 8192)  // 1 KB + 512 KB

struct RouterWS {
  unsigned int counts[NEXP];
  double z_sum;
  double ent_sum;
};

typedef _Float16 half8 __attribute__((ext_vector_type(8)));
typedef float floatx4 __attribute__((ext_vector_type(4)));

typedef __attribute__((address_space(1))) void v1_t;
typedef __attribute__((address_space(3))) void v3_t;
__device__ __forceinline__ void cp16(const void* g, void* l) {
  __builtin_amdgcn_global_load_lds((v1_t*)g, (v3_t*)l, 16, 0, 0);
}

// ---- prologue: split w*256 into 2 fp16 planes, fragment-ordered ----
// plane layout (halves): [s][p][t][l][8] ; lane l of etile t covers
// w[e=16t+(l&15)][k=32s+(l>>4)*8 .. +7].
__global__ void convert_w(const float* __restrict__ w, _Float16* __restrict__ wp) {
  int tid = blockIdx.x * 256 + threadIdx.x;  // 0..16383
  int l = tid & 63;
  int t = (tid >> 6) & 3;
  int s = tid >> 8;
  int e = 16 * t + (l & 15);
  int k0 = 32 * s + (l >> 4) * 8;
  const float* src = w + (size_t)e * DDIM + k0;
  half8 h, lo;
#pragma unroll
  for (int i = 0; i < 8; ++i) {
    float v = src[i] * 256.0f;
    _Float16 hh = (_Float16)v;
    h[i] = hh;
    lo[i] = (_Float16)(v - (float)hh);
  }
  size_t base = (size_t)s * 4096 + ((size_t)t * 64 + l) * 8;
  *(half8*)(wp + base) = h;
  *(half8*)(wp + base + 2048) = lo;  // plane 1
}

// ---- main MFMA kernel ----
__global__ __launch_bounds__(256, 2) void router_mfma(
    const float* __restrict__ x, const _Float16* __restrict__ wp,
    float* __restrict__ out, RouterWS* __restrict__ ws) {
  // w ring: 4 x 8KB ([0,4K) hi | [4K,8K) lo per buffer).
  // After the K loop, lg[64][68] (17.4KB) aliases the ring.
  __shared__ __align__(16) char smem[32768];
  __shared__ unsigned int hist[NEXP];

  const int tid = threadIdx.x;                              // 0..255
  const int l = tid & 63;
  const int wv = __builtin_amdgcn_readfirstlane(tid >> 6);  // m-tile 0..3
  const int r = l & 15;                                     // token row / expert col
  const int g = l >> 4;                                     // k-group

  const int tokb = blockIdx.x * 64;
  const float* xrow = x + (size_t)(tokb + wv * 16 + r) * DDIM + g * 8;
  const int wlo = 16 * l;

  floatx4 acc[4];
#pragma unroll
  for (int t = 0; t < 4; ++t) {
    floatx4 z = {0.f, 0.f, 0.f, 0.f};
    acc[t] = z;
  }

  float4 xA0, xA1, xB0, xB1;  // x fragment ping-pong (even/odd steps)

#define XLOAD(S, X0, X1)                                                       \
  {                                                                            \
    X0 = *(const float4*)(xrow + (size_t)(S) * 32);                            \
    X1 = *(const float4*)(xrow + (size_t)(S) * 32 + 4);                        \
  }

#define WSTAGE(S, WB)                                                          \
  {                                                                            \
    char* bb_ = smem + (WB) * 8192;                                            \
    const char* ws_ = (const char*)wp + (size_t)(S) * 8192 + tid * 16;         \
    cp16(ws_, bb_ + tid * 16);                                                 \
    cp16(ws_ + 4096, bb_ + 4096 + tid * 16);                                   \
  }

#define WAITBAR(NW)                                                            \
  asm volatile("s_waitcnt vmcnt(" #NW ")\n\ts_barrier" ::: "memory");          \
  __builtin_amdgcn_sched_barrier(0);

#define CVT8(X0, X1, XH, XL)                                                   \
  {                                                                            \
    float vv[8] = {X0.x, X0.y, X0.z, X0.w, X1.x, X1.y, X1.z, X1.w};            \
    _Pragma("unroll") for (int i = 0; i < 8; ++i) {                            \
      _Float16 hh = (_Float16)vv[i];                                           \
      XH[i] = hh;                                                              \
      XL[i] = (_Float16)(vv[i] - (float)hh);                                   \
    }                                                                          \
  }

#define MFMAS(WB, XH, XL)                                                      \
  {                                                                            \
    const char* wb_ = smem + (WB) * 8192;                                      \
    _Pragma("unroll") for (int t = 0; t < 4; ++t) {                            \
      half8 wh8 = *(const half8*)(wb_ + t * 1024 + wlo);                       \
      half8 wl8 = *(const half8*)(wb_ + 4096 + t * 1024 + wlo);                \
      acc[t] =                                                                 \
          __builtin_amdgcn_mfma_f32_16x16x32_f16(XH, wh8, acc[t], 0, 0, 0);    \
      acc[t] =                                                                 \
          __builtin_amdgcn_mfma_f32_16x16x32_f16(XH, wl8, acc[t], 0, 0, 0);    \
      acc[t] =                                                                 \
          __builtin_amdgcn_mfma_f32_16x16x32_f16(XL, wh8, acc[t], 0, 0, 0);    \
      acc[t] =                                                                 \
          __builtin_amdgcn_mfma_f32_16x16x32_f16(XL, wl8, acc[t], 0, 0, 0);    \
    }                                                                          \
  }

  // STEP: cvt x(S) (consumes X regs) -> refill X with x(S+2) -> stage w(S+3)
  // -> MFMA from w buf -> counted wait + barrier.
#define STEP(S, WB, X0, X1, NW)                                                \
  {                                                                            \
    half8 xh, xl;                                                              \
    CVT8(X0, X1, xh, xl);                                                      \
    XLOAD((S) + 2, X0, X1)                                                     \
    WSTAGE((S) + 3, (((S) + 3) & 3))                                           \
    MFMAS(WB, xh, xl)                                                          \
    WAITBAR(NW)                                                                \
  }

  // ---- prologue: x0,x1 to regs; w stages 0,1,2; need w0 -> vmcnt(4) ----
  XLOAD(0, xA0, xA1)
  XLOAD(1, xB0, xB1)
  WSTAGE(0, 0)
  WSTAGE(1, 1)
  WSTAGE(2, 2)
  if (tid < NEXP) hist[tid] = 0;
  WAITBAR(4)

  STEP(0, 0, xA0, xA1, 6)  // stages w3; need w1 -> 6 newer
  for (int b = 1; b < 58; b += 4) {  // steps 1..60, uniform wait(8)
    STEP(b + 0, 1, xB0, xB1, 8)
    STEP(b + 1, 2, xA0, xA1, 8)
    STEP(b + 2, 3, xB0, xB1, 8)
    STEP(b + 3, 0, xA0, xA1, 8)
  }
  {  // step 61: no w stage; load x63; need w62 -> 6 newer
    half8 xh, xl;
    CVT8(xB0, xB1, xh, xl);
    XLOAD(63, xB0, xB1)
    MFMAS(1, xh, xl)
    WAITBAR(6)
  }
  {  // step 62: nothing issued; need w63 -> 2 newer (x63)
    half8 xh, xl;
    CVT8(xA0, xA1, xh, xl);
    MFMAS(2, xh, xl)
    WAITBAR(2)
  }
  {  // step 63: all resident
    half8 xh, xl;
    CVT8(xB0, xB1, xh, xl);
    MFMAS(3, xh, xl)
  }
  __syncthreads();

#undef STEP
#undef MFMAS
#undef CVT8
#undef WAITBAR
#undef WSTAGE
#undef XLOAD

  // C layout (HW-verified): col = lane&15, row = (lane>>4)*4 + j.
  // lg[token][expert]: token = wv*16 + g*4 + j, expert = 16t + r. Scale 1/256.
  float* lg = (float*)smem;
#pragma unroll
  for (int t = 0; t < 4; ++t)
#pragma unroll
    for (int j = 0; j < 4; ++j)
      lg[(wv * 16 + g * 4 + j) * LG_STRIDE + 16 * t + r] = acc[t][j] * 0.00390625f;
  __syncthreads();

  if (tid < 64) {  // wave 0: one token per lane, serial over 64 experts
    const int t = tid;
    const float* Lg = &lg[t * LG_STRIDE];

    float m1 = Lg[0];
    int i1 = 0;
    for (int e = 1; e < NEXP; ++e) {
      float v = Lg[e];
      if (v > m1) { m1 = v; i1 = e; }  // strict > keeps lowest index on ties
    }
    float m2 = -3.4e38f;
    int i2 = 0;
    for (int e = 0; e < NEXP; ++e) {
      if (e == i1) continue;
      float v = Lg[e];
      if (v > m2) { m2 = v; i2 = e; }
    }

    float s = 0.f;
    for (int e = 0; e < NEXP; ++e) s += expf(Lg[e] - m1);
    float p1 = expf(Lg[i1] - m1) / s;
    float p2 = expf(Lg[i2] - m1) / s;
    float wsum = p1 + p2 + 1e-8f;
    float w1 = p1 / wsum;
    float w2 = p2 / wsum;

    float ent = 0.f;
    for (int e = 0; e < NEXP; ++e) {
      float p = expf(Lg[e] - m1) / s;
      ent -= p * logf(p + 1e-10f);
    }
    float lse = m1 + logf(s);

    size_t gt = (size_t)blockIdx.x * 64 + t;
    out[OFF_IDX + gt * 2 + 0] = (float)i1;
    out[OFF_IDX + gt * 2 + 1] = (float)i2;
    out[OFF_W + gt * 2 + 0] = w1;
    out[OFF_W + gt * 2 + 1] = w2;
    out[OFF_CONF + gt] = fmaxf(w1, w2);

    atomicAdd(&hist[i1], 1u);
    atomicAdd(&hist[i2], 1u);

    float zv = lse, ev = ent;
#pragma unroll
    for (int o = 32; o > 0; o >>= 1) {
      zv += __shfl_down(zv, o);
      ev += __shfl_down(ev, o);
    }
    if (t == 0) {
      atomicAdd(&ws->z_sum, (double)zv);
      atomicAdd(&ws->ent_sum, (double)ev);
    }
  }
  __syncthreads();
  if (tid < NEXP) atomicAdd(&ws->counts[tid], hist[tid]);
}

// ---- fp32 fallback (R10) if ws too small for planes ----
#define TTILE 128
#define KB 32
#define NCH (DDIM / KB)
#define XSTR 36
#define XBUF (TTILE * XSTR)
#define WBUF (NEXP * XSTR)
#define WOFF (2 * XBUF)

__global__ __launch_bounds__(512, 4) void router_fp32(
    const float* __restrict__ x, const float* __restrict__ w,
    float* __restrict__ out, RouterWS* __restrict__ ws) {
  __shared__ float smem[2 * XBUF + 2 * WBUF];
  __shared__ unsigned int hist[NEXP];

  const int tid = threadIdx.x;
  const int L = tid & 63;
  const int wv = __builtin_amdgcn_readfirstlane(tid >> 6);
  const float* xg = x + (size_t)blockIdx.x * TTILE * DDIM;
  const int sr = tid >> 3;
  const int sc = (tid & 7) * 4;

  float4 rx0 = *(const float4*)(xg + (size_t)sr * DDIM + sc);
  float4 rx1 = *(const float4*)(xg + (size_t)(sr + 64) * DDIM + sc);
  float4 rw = *(const float4*)(w + (size_t)sr * DDIM + sc);
  *(float4*)&smem[sr * XSTR + sc] = rx0;
  *(float4*)&smem[(sr + 64) * XSTR + sc] = rx1;
  *(float4*)&smem[WOFF + sr * XSTR + sc] = rw;

  float acc0[8], acc1[8];
#pragma unroll
  for (int e = 0; e < 8; ++e) { acc0[e] = 0.f; acc1[e] = 0.f; }
  __syncthreads();

  for (int c = 0; c < NCH; ++c) {
    const int cxb = (c & 1) * XBUF;
    const int cwb = WOFF + (c & 1) * WBUF;
    if (c + 1 < NCH) {
      int k0 = (c + 1) * KB;
      rx0 = *(const float4*)(xg + (size_t)sr * DDIM + k0 + sc);
      rx1 = *(const float4*)(xg + (size_t)(sr + 64) * DDIM + k0 + sc);
      rw = *(const float4*)(w + (size_t)sr * DDIM + k0 + sc);
    }
    float4 xr0[8], xr1[8];
#pragma unroll
    for (int m = 0; m < 8; ++m) {
      xr0[m] = *(const float4*)&smem[cxb + L * XSTR + 4 * m];
      xr1[m] = *(const float4*)&smem[cxb + (L + 64) * XSTR + 4 * m];
    }
#pragma unroll
    for (int e = 0; e < 8; ++e) {
      const float* wrow = &smem[cwb + (8 * wv + e) * XSTR];
      float a0 = acc0[e], a1 = acc1[e];
#pragma unroll
      for (int m = 0; m < 8; ++m) {
        float4 wq = *(const float4*)&wrow[4 * m];
        a0 = fmaf(xr0[m].x, wq.x, a0);
        a0 = fmaf(xr0[m].y, wq.y, a0);
        a0 = fmaf(xr0[m].z, wq.z, a0);
        a0 = fmaf(xr0[m].w, wq.w, a0);
        a1 = fmaf(xr1[m].x, wq.x, a1);
        a1 = fmaf(xr1[m].y, wq.y, a1);
        a1 = fmaf(xr1[m].z, wq.z, a1);
        a1 = fmaf(xr1[m].w, wq.w, a1);
      }
      acc0[e] = a0;
      acc1[e] = a1;
    }
    if (c + 1 < NCH) {
      const int nxb = ((c + 1) & 1) * XBUF;
      const int nwb = WOFF + ((c + 1) & 1) * WBUF;
      *(float4*)&smem[nxb + sr * XSTR + sc] = rx0;
      *(float4*)&smem[nxb + (sr + 64) * XSTR + sc] = rx1;
      *(float4*)&smem[nwb + sr * XSTR + sc] = rw;
    }
    __syncthreads();
  }

#pragma unroll
  for (int e = 0; e < 8; ++e) {
    smem[L * LG_STRIDE + wv * 8 + e] = acc0[e];
    smem[(L + 64) * LG_STRIDE + wv * 8 + e] = acc1[e];
  }
  if (tid < NEXP) hist[tid] = 0;
  __syncthreads();

  if (tid < TTILE) {
    const int t = tid;
    const float* Lg = &smem[t * LG_STRIDE];
    float m1 = Lg[0];
    int i1 = 0;
    for (int e = 1; e < NEXP; ++e) {
      float v = Lg[e];
      if (v > m1) { m1 = v; i1 = e; }
    }
    float m2 = -3.4e38f;
    int i2 = 0;
    for (int e = 0; e < NEXP; ++e) {
      if (e == i1) continue;
      float v = Lg[e];
      if (v > m2) { m2 = v; i2 = e; }
    }
    float s = 0.f;
    for (int e = 0; e < NEXP; ++e) s += expf(Lg[e] - m1);
    float p1 = expf(Lg[i1] - m1) / s;
    float p2 = expf(Lg[i2] - m1) / s;
    float wsum = p1 + p2 + 1e-8f;
    float w1 = p1 / wsum;
    float w2 = p2 / wsum;
    float ent = 0.f;
    for (int e = 0; e < NEXP; ++e) {
      float p = expf(Lg[e] - m1) / s;
      ent -= p * logf(p + 1e-10f);
    }
    float lse = m1 + logf(s);
    size_t gt = (size_t)blockIdx.x * TTILE + t;
    out[OFF_IDX + gt * 2 + 0] = (float)i1;
    out[OFF_IDX + gt * 2 + 1] = (float)i2;
    out[OFF_W + gt * 2 + 0] = w1;
    out[OFF_W + gt * 2 + 1] = w2;
    out[OFF_CONF + gt] = fmaxf(w1, w2);
    atomicAdd(&hist[i1], 1u);
    atomicAdd(&hist[i2], 1u);
    float zv = lse, ev = ent;
#pragma unroll
    for (int o = 32; o > 0; o >>= 1) {
      zv += __shfl_down(zv, o);
      ev += __shfl_down(ev, o);
    }
    if ((tid & 63) == 0) {
      atomicAdd(&ws->z_sum, (double)zv);
      atomicAdd(&ws->ent_sum, (double)ev);
    }
  }
  __syncthreads();
  if (tid < NEXP) atomicAdd(&ws->counts[tid], hist[tid]);
}

__global__ void router_final(float* __restrict__ out, RouterWS* __restrict__ ws) {
  int e = threadIdx.x;  // 64 threads
  float c = (float)ws->counts[e];
  out[OFF_CNT + e] = c;
  float over = fmaxf(c - 1280.f, 0.f);   // capacity = int(1.25*32768/64*2)
  float ld = c / 65536.f - (1.f / 64.f);
  float so = over, sv = ld * ld;
#pragma unroll
  for (int o = 32; o > 0; o >>= 1) {
    so += __shfl_down(so, o);
    sv += __shfl_down(sv, o);
  }
  if (e == 0) {
    out[OFF_OVF] = so / 32768.f * 100.f;
    out[OFF_VAR] = sv / 64.f;
    out[OFF_ZL] = (float)(ws->z_sum / 32768.0 * 0.01);
    out[OFF_ENT] = (float)(ws->ent_sum / 32768.0);
  }
}

extern "C" void kernel_launch(void* const* d_in, const int* in_sizes, int n_in,
                              void* d_out, int out_size, void* d_ws, size_t ws_size,
                              hipStream_t stream) {
  const float* x = (const float*)d_in[0];   // hidden_states [4,8192,2048] f32
  const float* w = (const float*)d_in[1];   // gate_weight [64,2048] f32
  float* out = (float*)d_out;
  RouterWS* ws = (RouterWS*)d_ws;

  (void)hipMemsetAsync(d_ws, 0, sizeof(RouterWS), stream);
  if (ws_size >= (size_t)WS_NEEDED) {
    _Float16* wp = (_Float16*)((char*)d_ws + WS_PLANES_OFF);
    hipLaunchKernelGGL(convert_w, dim3(64), dim3(256), 0, stream, w, wp);
    hipLaunchKernelGGL(router_mfma, dim3(NTOK / 64), dim3(256), 0, stream,
                       x, wp, out, ws);
  } else {
    hipLaunchKernelGGL(router_fp32, dim3(NTOK / TTILE), dim3(512), 0, stream,
                       x, w, out, ws);
  }
  hipLaunchKernelGGL(router_final, dim3(1), dim3(64), 0, stream, out, ws);
}

// Round 18
// 74.842 us; speedup vs baseline: 1.2097x; 1.0995x over previous
//
#include <hip/hip_runtime.h>

// TopKRouter: N=32768 tokens, D=2048, E=64, K=2.
// FINAL = R14 champion (75.4 us), restored byte-for-byte.
//  - fp16x2-split MFMA (4 products hh,hl,lh,ll; ~2^-22-exact vs fp32).
//  - convert_w prologue: w*256 -> 2 fp16 planes, fragment-ordered, in d_ws.
//  - x AND w staged HBM/L2 -> LDS via global_load_lds, 4-deep ring
//    (16KB/buf: 8KB x + 8KB w), stage(s+3) issued at step s.
//  - end-of-step sync = asm s_waitcnt vmcnt(8) + raw s_barrier +
//    sched_barrier(0): never drains the x stream (T3/T4). Tail: 4, 0.
//  - x LDS layout float4-XOR swizzled (pre-swizzled global source, linear
//    dest): conflict-free ds_read_b128. w fragment-ordered (conflict-free).

#define NTOK 32768
#define DDIM 2048
#define NEXP 64
#define NKS 64              // K steps of 32
#define LG_STRIDE 68        // 64 + 4 pad

#define OFF_IDX 0
#define OFF_W 65536
#define OFF_CNT 131072
#define OFF_OVF 131136
#define OFF_ZL 131137
#define OFF_ENT 131138
#define OFF_VAR 131139
#define OFF_CONF 131140

#define WS_PLANES_OFF 1024
#define WS_NEEDED (WS_PLANES_OFF + NKS * 8192)  // 1 KB + 512 KB

struct RouterWS {
  unsigned int counts[NEXP];
  double z_sum;
  double ent_sum;
};

typedef _Float16 half8 __attribute__((ext_vector_type(8)));
typedef float floatx4 __attribute__((ext_vector_type(4)));

typedef __attribute__((address_space(1))) void v1_t;
typedef __attribute__((address_space(3))) void v3_t;
__device__ __forceinline__ void cp16(const void* g, void* l) {
  __builtin_amdgcn_global_load_lds((v1_t*)g, (v3_t*)l, 16, 0, 0);
}

// ---- prologue: split w*256 into 2 fp16 planes, fragment-ordered ----
// plane layout (halves): [s][p][t][l][8] ; lane l of etile t covers
// w[e=16t+(l&15)][k=32s+(l>>4)*8 .. +7].
__global__ void convert_w(const float* __restrict__ w, _Float16* __restrict__ wp) {
  int tid = blockIdx.x * 256 + threadIdx.x;  // 0..16383
  int l = tid & 63;
  int t = (tid >> 6) & 3;
  int s = tid >> 8;
  int e = 16 * t + (l & 15);
  int k0 = 32 * s + (l >> 4) * 8;
  const float* src = w + (size_t)e * DDIM + k0;
  half8 h, lo;
#pragma unroll
  for (int i = 0; i < 8; ++i) {
    float v = src[i] * 256.0f;
    _Float16 hh = (_Float16)v;
    h[i] = hh;
    lo[i] = (_Float16)(v - (float)hh);
  }
  size_t base = (size_t)s * 4096 + ((size_t)t * 64 + l) * 8;
  *(half8*)(wp + base) = h;
  *(half8*)(wp + base + 2048) = lo;  // plane 1
}

// ---- main MFMA kernel ----
__global__ __launch_bounds__(256, 2) void router_mfma(
    const float* __restrict__ x, const _Float16* __restrict__ wp,
    float* __restrict__ out, RouterWS* __restrict__ ws) {
  // 4 ring buffers x 16KB: [0,8K) x-tile (swizzled), [8K,12K) w hi, [12K,16K) w lo.
  // After the K loop, lg[64][68] (17.4KB) aliases the front.
  __shared__ __align__(16) char smem[65536];
  __shared__ unsigned int hist[NEXP];

  const int tid = threadIdx.x;                              // 0..255
  const int l = tid & 63;
  const int wv = __builtin_amdgcn_readfirstlane(tid >> 6);  // mtile 0..3
  const int r = l & 15;                                     // token row / expert col
  const int g = l >> 4;                                     // k-group

  const int tokb = blockIdx.x * 64;
  const float* xg = x + (size_t)tokb * DDIM;

  // staging constants: thread stages x slots tid (rows 0..31) and tid+256
  // (rows 32..63); slot i = row*8 + (j ^ (row&7)) float4s, source pre-swizzled.
  const int srow0 = tid >> 3;
  const int srow1 = srow0 + 32;
  const int sj = tid & 7;
  const size_t gx0 = (size_t)srow0 * DDIM + 4 * (sj ^ (srow0 & 7));
  const size_t gx1 = (size_t)srow1 * DDIM + 4 * (sj ^ (srow1 & 7));

  // read constants: lane (r,g) of wave wv reads row=wv*16+r, float4 cols 2g,2g+1
  const int row = wv * 16 + r;
  const int rs = row & 7;
  const int so0 = 16 * (row * 8 + ((2 * g) ^ rs));
  const int so1 = 16 * (row * 8 + ((2 * g + 1) ^ rs));
  const int wlo = 16 * l;

  floatx4 acc[4];
#pragma unroll
  for (int t = 0; t < 4; ++t) {
    floatx4 z = {0.f, 0.f, 0.f, 0.f};
    acc[t] = z;
  }

#define STAGE(S, BUF)                                                          \
  {                                                                            \
    char* bb_ = smem + (BUF) * 16384;                                          \
    cp16(xg + (size_t)(S) * 32 + gx0, bb_ + tid * 16);                         \
    cp16(xg + (size_t)(S) * 32 + gx1, bb_ + 4096 + tid * 16);                  \
    const char* wsrc_ = (const char*)wp + (size_t)(S) * 8192 + tid * 16;       \
    cp16(wsrc_, bb_ + 8192 + tid * 16);                                        \
    cp16(wsrc_ + 4096, bb_ + 12288 + tid * 16);                                \
  }

#define WAITBAR(NW)                                                            \
  asm volatile("s_waitcnt vmcnt(" #NW ")\n\ts_barrier" ::: "memory");          \
  __builtin_amdgcn_sched_barrier(0);

#define CVT8(X0, X1, XH, XL)                                                   \
  {                                                                            \
    float vv[8] = {X0.x, X0.y, X0.z, X0.w, X1.x, X1.y, X1.z, X1.w};            \
    _Pragma("unroll") for (int i = 0; i < 8; ++i) {                            \
      _Float16 hh = (_Float16)vv[i];                                           \
      XH[i] = hh;                                                              \
      XL[i] = (_Float16)(vv[i] - (float)hh);                                   \
    }                                                                          \
  }

#define COMPUTE(BUF)                                                           \
  const char* bb = smem + (BUF) * 16384;                                       \
  float4 xq0 = *(const float4*)(bb + so0);                                     \
  float4 xq1 = *(const float4*)(bb + so1);                                     \
  half8 xh, xl;                                                                \
  CVT8(xq0, xq1, xh, xl);                                                      \
  _Pragma("unroll") for (int t = 0; t < 4; ++t) {                              \
    half8 wh = *(const half8*)(bb + 8192 + 1024 * t + wlo);                    \
    half8 wl = *(const half8*)(bb + 12288 + 1024 * t + wlo);                   \
    acc[t] = __builtin_amdgcn_mfma_f32_16x16x32_f16(xh, wh, acc[t], 0, 0, 0);  \
    acc[t] = __builtin_amdgcn_mfma_f32_16x16x32_f16(xh, wl, acc[t], 0, 0, 0);  \
    acc[t] = __builtin_amdgcn_mfma_f32_16x16x32_f16(xl, wh, acc[t], 0, 0, 0);  \
    acc[t] = __builtin_amdgcn_mfma_f32_16x16x32_f16(xl, wl, acc[t], 0, 0, 0);  \
  }

#define STEP(S, BUF, NW)                                                       \
  {                                                                            \
    STAGE((S) + 3, (((S) + 3) & 3));                                           \
    COMPUTE(BUF)                                                               \
    WAITBAR(NW)                                                                \
  }
#define STEPN(S, BUF, NW)  /* tail: no stage */                                \
  {                                                                            \
    COMPUTE(BUF)                                                               \
    WAITBAR(NW)                                                                \
  }

  // prologue: stages 0,1,2 in flight; wait until stage 0 lands.
  STAGE(0, 0)
  STAGE(1, 1)
  STAGE(2, 2)
  if (tid < NEXP) hist[tid] = 0;
  WAITBAR(8)

  for (int ss = 0; ss < 60; ss += 4) {  // ss = 0..56; steps 0..59
    STEP(ss, 0, 8)
    STEP(ss + 1, 1, 8)
    STEP(ss + 2, 2, 8)
    STEP(ss + 3, 3, 8)
  }
  STEP(60, 0, 8)    // stages 63
  STEPN(61, 1, 4)   // need stage 62 done
  STEPN(62, 2, 0)   // need stage 63 done
  {                 // step 63: nothing outstanding
    COMPUTE(3)
  }
  __syncthreads();

#undef STEP
#undef STEPN
#undef COMPUTE
#undef CVT8
#undef WAITBAR
#undef STAGE

  // C layout (HW-verified): col = lane&15, row = (lane>>4)*4 + j.
  // lg[token][expert], token = wv*16 + g*4 + j, expert = 16t + r. Scale 1/256.
  float* lg = (float*)smem;
#pragma unroll
  for (int t = 0; t < 4; ++t)
#pragma unroll
    for (int j = 0; j < 4; ++j)
      lg[(wv * 16 + g * 4 + j) * LG_STRIDE + 16 * t + r] = acc[t][j] * 0.00390625f;
  __syncthreads();

  if (tid < 64) {  // wave 0: one token per lane, serial over 64 experts
    const int t = tid;
    const float* Lg = &lg[t * LG_STRIDE];

    float m1 = Lg[0];
    int i1 = 0;
    for (int e = 1; e < NEXP; ++e) {
      float v = Lg[e];
      if (v > m1) { m1 = v; i1 = e; }  // strict > keeps lowest index on ties
    }
    float m2 = -3.4e38f;
    int i2 = 0;
    for (int e = 0; e < NEXP; ++e) {
      if (e == i1) continue;
      float v = Lg[e];
      if (v > m2) { m2 = v; i2 = e; }
    }

    float s = 0.f;
    for (int e = 0; e < NEXP; ++e) s += expf(Lg[e] - m1);
    float p1 = expf(Lg[i1] - m1) / s;
    float p2 = expf(Lg[i2] - m1) / s;
    float wsum = p1 + p2 + 1e-8f;
    float w1 = p1 / wsum;
    float w2 = p2 / wsum;

    float ent = 0.f;
    for (int e = 0; e < NEXP; ++e) {
      float p = expf(Lg[e] - m1) / s;
      ent -= p * logf(p + 1e-10f);
    }
    float lse = m1 + logf(s);

    size_t gt = (size_t)blockIdx.x * 64 + t;
    out[OFF_IDX + gt * 2 + 0] = (float)i1;
    out[OFF_IDX + gt * 2 + 1] = (float)i2;
    out[OFF_W + gt * 2 + 0] = w1;
    out[OFF_W + gt * 2 + 1] = w2;
    out[OFF_CONF + gt] = fmaxf(w1, w2);

    atomicAdd(&hist[i1], 1u);
    atomicAdd(&hist[i2], 1u);

    float zv = lse, ev = ent;
#pragma unroll
    for (int o = 32; o > 0; o >>= 1) {
      zv += __shfl_down(zv, o);
      ev += __shfl_down(ev, o);
    }
    if (t == 0) {
      atomicAdd(&ws->z_sum, (double)zv);
      atomicAdd(&ws->ent_sum, (double)ev);
    }
  }
  __syncthreads();
  if (tid < NEXP) atomicAdd(&ws->counts[tid], hist[tid]);
}

// ---- fp32 fallback (R10) if ws too small for planes ----
#define TTILE 128
#define KB 32
#define NCH (DDIM / KB)
#define XSTR 36
#define XBUF (TTILE * XSTR)
#define WBUF (NEXP * XSTR)
#define WOFF (2 * XBUF)

__global__ __launch_bounds__(512, 4) void router_fp32(
    const float* __restrict__ x, const float* __restrict__ w,
    float* __restrict__ out, RouterWS* __restrict__ ws) {
  __shared__ float smem[2 * XBUF + 2 * WBUF];
  __shared__ unsigned int hist[NEXP];

  const int tid = threadIdx.x;
  const int L = tid & 63;
  const int wv = __builtin_amdgcn_readfirstlane(tid >> 6);
  const float* xg = x + (size_t)blockIdx.x * TTILE * DDIM;
  const int sr = tid >> 3;
  const int sc = (tid & 7) * 4;

  float4 rx0 = *(const float4*)(xg + (size_t)sr * DDIM + sc);
  float4 rx1 = *(const float4*)(xg + (size_t)(sr + 64) * DDIM + sc);
  float4 rw = *(const float4*)(w + (size_t)sr * DDIM + sc);
  *(float4*)&smem[sr * XSTR + sc] = rx0;
  *(float4*)&smem[(sr + 64) * XSTR + sc] = rx1;
  *(float4*)&smem[WOFF + sr * XSTR + sc] = rw;

  float acc0[8], acc1[8];
#pragma unroll
  for (int e = 0; e < 8; ++e) { acc0[e] = 0.f; acc1[e] = 0.f; }
  __syncthreads();

  for (int c = 0; c < NCH; ++c) {
    const int cxb = (c & 1) * XBUF;
    const int cwb = WOFF + (c & 1) * WBUF;
    if (c + 1 < NCH) {
      int k0 = (c + 1) * KB;
      rx0 = *(const float4*)(xg + (size_t)sr * DDIM + k0 + sc);
      rx1 = *(const float4*)(xg + (size_t)(sr + 64) * DDIM + k0 + sc);
      rw = *(const float4*)(w + (size_t)sr * DDIM + k0 + sc);
    }
    float4 xr0[8], xr1[8];
#pragma unroll
    for (int m = 0; m < 8; ++m) {
      xr0[m] = *(const float4*)&smem[cxb + L * XSTR + 4 * m];
      xr1[m] = *(const float4*)&smem[cxb + (L + 64) * XSTR + 4 * m];
    }
#pragma unroll
    for (int e = 0; e < 8; ++e) {
      const float* wrow = &smem[cwb + (8 * wv + e) * XSTR];
      float a0 = acc0[e], a1 = acc1[e];
#pragma unroll
      for (int m = 0; m < 8; ++m) {
        float4 wq = *(const float4*)&wrow[4 * m];
        a0 = fmaf(xr0[m].x, wq.x, a0);
        a0 = fmaf(xr0[m].y, wq.y, a0);
        a0 = fmaf(xr0[m].z, wq.z, a0);
        a0 = fmaf(xr0[m].w, wq.w, a0);
        a1 = fmaf(xr1[m].x, wq.x, a1);
        a1 = fmaf(xr1[m].y, wq.y, a1);
        a1 = fmaf(xr1[m].z, wq.z, a1);
        a1 = fmaf(xr1[m].w, wq.w, a1);
      }
      acc0[e] = a0;
      acc1[e] = a1;
    }
    if (c + 1 < NCH) {
      const int nxb = ((c + 1) & 1) * XBUF;
      const int nwb = WOFF + ((c + 1) & 1) * WBUF;
      *(float4*)&smem[nxb + sr * XSTR + sc] = rx0;
      *(float4*)&smem[nxb + (sr + 64) * XSTR + sc] = rx1;
      *(float4*)&smem[nwb + sr * XSTR + sc] = rw;
    }
    __syncthreads();
  }

#pragma unroll
  for (int e = 0; e < 8; ++e) {
    smem[L * LG_STRIDE + wv * 8 + e] = acc0[e];
    smem[(L + 64) * LG_STRIDE + wv * 8 + e] = acc1[e];
  }
  if (tid < NEXP) hist[tid] = 0;
  __syncthreads();

  if (tid < TTILE) {
    const int t = tid;
    const float* Lg = &smem[t * LG_STRIDE];
    float m1 = Lg[0];
    int i1 = 0;
    for (int e = 1; e < NEXP; ++e) {
      float v = Lg[e];
      if (v > m1) { m1 = v; i1 = e; }
    }
    float m2 = -3.4e38f;
    int i2 = 0;
    for (int e = 0; e < NEXP; ++e) {
      if (e == i1) continue;
      float v = Lg[e];
      if (v > m2) { m2 = v; i2 = e; }
    }
    float s = 0.f;
    for (int e = 0; e < NEXP; ++e) s += expf(Lg[e] - m1);
    float p1 = expf(Lg[i1] - m1) / s;
    float p2 = expf(Lg[i2] - m1) / s;
    float wsum = p1 + p2 + 1e-8f;
    float w1 = p1 / wsum;
    float w2 = p2 / wsum;
    float ent = 0.f;
    for (int e = 0; e < NEXP; ++e) {
      float p = expf(Lg[e] - m1) / s;
      ent -= p * logf(p + 1e-10f);
    }
    float lse = m1 + logf(s);
    size_t gt = (size_t)blockIdx.x * TTILE + t;
    out[OFF_IDX + gt * 2 + 0] = (float)i1;
    out[OFF_IDX + gt * 2 + 1] = (float)i2;
    out[OFF_W + gt * 2 + 0] = w1;
    out[OFF_W + gt * 2 + 1] = w2;
    out[OFF_CONF + gt] = fmaxf(w1, w2);
    atomicAdd(&hist[i1], 1u);
    atomicAdd(&hist[i2], 1u);
    float zv = lse, ev = ent;
#pragma unroll
    for (int o = 32; o > 0; o >>= 1) {
      zv += __shfl_down(zv, o);
      ev += __shfl_down(ev, o);
    }
    if ((tid & 63) == 0) {
      atomicAdd(&ws->z_sum, (double)zv);
      atomicAdd(&ws->ent_sum, (double)ev);
    }
  }
  __syncthreads();
  if (tid < NEXP) atomicAdd(&ws->counts[tid], hist[tid]);
}

__global__ void router_final(float* __restrict__ out, RouterWS* __restrict__ ws) {
  int e = threadIdx.x;  // 64 threads
  float c = (float)ws->counts[e];
  out[OFF_CNT + e] = c;
  float over = fmaxf(c - 1280.f, 0.f);   // capacity = int(1.25*32768/64*2)
  float ld = c / 65536.f - (1.f / 64.f);
  float so = over, sv = ld * ld;
#pragma unroll
  for (int o = 32; o > 0; o >>= 1) {
    so += __shfl_down(so, o);
    sv += __shfl_down(sv, o);
  }
  if (e == 0) {
    out[OFF_OVF] = so / 32768.f * 100.f;
    out[OFF_VAR] = sv / 64.f;
    out[OFF_ZL] = (float)(ws->z_sum / 32768.0 * 0.01);
    out[OFF_ENT] = (float)(ws->ent_sum / 32768.0);
  }
}

extern "C" void kernel_launch(void* const* d_in, const int* in_sizes, int n_in,
                              void* d_out, int out_size, void* d_ws, size_t ws_size,
                              hipStream_t stream) {
  const float* x = (const float*)d_in[0];   // hidden_states [4,8192,2048] f32
  const float* w = (const float*)d_in[1];   // gate_weight [64,2048] f32
  float* out = (float*)d_out;
  RouterWS* ws = (RouterWS*)d_ws;

  (void)hipMemsetAsync(d_ws, 0, sizeof(RouterWS), stream);
  if (ws_size >= (size_t)WS_NEEDED) {
    _Float16* wp = (_Float16*)((char*)d_ws + WS_PLANES_OFF);
    hipLaunchKernelGGL(convert_w, dim3(64), dim3(256), 0, stream, w, wp);
    hipLaunchKernelGGL(router_mfma, dim3(NTOK / 64), dim3(256), 0, stream,
                       x, wp, out, ws);
  } else {
    hipLaunchKernelGGL(router_fp32, dim3(NTOK / TTILE), dim3(512), 0, stream,
                       x, w, out, ws);
  }
  hipLaunchKernelGGL(router_final, dim3(1), dim3(64), 0, stream, out, ws);
}